// Round 1
// baseline (2810.287 us; speedup 1.0000x reference)
//
#include <hip/hip_runtime.h>
#include <stdint.h>

#define BATCH 512
#define SEQ   512
#define HID   128
#define NGATE 512   // 4*HID

typedef _Float16 half2v __attribute__((ext_vector_type(2)));

union UH2 { uint32_t u; half2v h; };

__device__ __forceinline__ uint32_t pack2(float x, float y){
  UH2 r; r.h[0] = (_Float16)x; r.h[1] = (_Float16)y; return r.u;
}

__device__ __forceinline__ float fdot2(uint32_t a, uint32_t b, float c){
  UH2 ua, ub; ua.u = a; ub.u = b;
#if __has_builtin(__builtin_amdgcn_fdot2)
  return __builtin_amdgcn_fdot2(ua.h, ub.h, c, false);
#else
  return c + (float)ua.h[0]*(float)ub.h[0] + (float)ua.h[1]*(float)ub.h[1];
#endif
}

__device__ __forceinline__ float sigm(float x){
  x = fminf(15.f, fmaxf(-15.f, x));
  return 1.f/(1.f + __expf(-x));
}
__device__ __forceinline__ float tanh_(float x){
  x = fminf(15.f, fmaxf(-15.f, x));
  const float e = __expf(-2.f*x);
  return (1.f - e)/(1.f + e);
}

// One LSTM layer, persistent over time. Grid: 256 blocks x 512 threads.
// Block owns batch rows b0, b0+1. Thread tid owns gate row n = tid
// (weights register-resident as packed f16 pairs).
__global__ __launch_bounds__(512, 2) void lstm_layer_kernel(
    const float* __restrict__ Wih, const float* __restrict__ Whh,
    const float* __restrict__ bih, const float* __restrict__ bhh,
    const float* __restrict__ x_in,   // layer0: (B,S,IN) fp32, else nullptr
    const uint32_t* h_in,             // layers1,2: packed f16x2 [S][B][64]
    uint32_t* h_out,                  // packed f16x2 [S][B][64], or nullptr
    float* y_out)                     // final: (S,H,B) fp32, or nullptr
{
  const int tid = threadIdx.x;
  const int b0  = blockIdx.x * 2;

  __shared__ uint4 in4[2][16];   // input activations, f16x2 packed (2 rows x 128)
  __shared__ uint4 hh4[2][16];   // h state, f16x2 packed
  __shared__ float gl[2][NGATE]; // gate pre-activations exchange

  uint32_t* inu = (uint32_t*)in4;
  uint32_t* hhu = (uint32_t*)hh4;

  // ---- load this thread's weight rows (gate n = tid), convert to f16 pairs
  uint32_t wih[64], whh[64];
  {
    const float2* wi2 = (const float2*)(Wih + tid*HID);
    const float2* wh2 = (const float2*)(Whh + tid*HID);
    #pragma unroll
    for (int p = 0; p < 64; ++p){ float2 a = wi2[p]; wih[p] = pack2(a.x, a.y); }
    #pragma unroll
    for (int p = 0; p < 64; ++p){ float2 a = wh2[p]; whh[p] = pack2(a.x, a.y); }
  }
  const float bias = bih[tid] + bhh[tid];

  // ---- init h state (zeros)
  if (tid < 32) ((uint4*)hh4)[tid] = make_uint4(0u,0u,0u,0u);

  float cA = 0.f, cB = 0.f;  // cell state, owned by threads tid<128 (2 units each)

  auto load_in = [&](int t){
    if (tid >= 128 && tid < 256){
      const int r = (tid >> 6) & 1, p = tid & 63, b = b0 + r;
      uint32_t v;
      if (x_in){
        const float2 xv = ((const float2*)(x_in + ((size_t)b*SEQ + t)*HID))[p];
        v = pack2(xv.x, xv.y);
      } else {
        v = h_in[(((size_t)t)*BATCH + b)*64 + p];
      }
      inu[r*64 + p] = v;
    }
  };

  load_in(0);

#define DOT8(W, SRC, Q) do { \
    const uint4 va_ = SRC[0][Q]; \
    const uint4 vb_ = SRC[1][Q]; \
    a0 = fdot2(W[4*(Q)+0], va_.x, a0); \
    a0 = fdot2(W[4*(Q)+1], va_.y, a0); \
    a0 = fdot2(W[4*(Q)+2], va_.z, a0); \
    a0 = fdot2(W[4*(Q)+3], va_.w, a0); \
    a1 = fdot2(W[4*(Q)+0], vb_.x, a1); \
    a1 = fdot2(W[4*(Q)+1], vb_.y, a1); \
    a1 = fdot2(W[4*(Q)+2], vb_.z, a1); \
    a1 = fdot2(W[4*(Q)+3], vb_.w, a1); \
  } while(0)

  for (int t = 0; t < SEQ; ++t){
    __syncthreads();   // in/h ready -> gate compute

    float a0 = bias, a1 = bias;
    #pragma unroll
    for (int q = 0; q < 16; ++q){ DOT8(wih, in4, q); }
    #pragma unroll
    for (int q = 0; q < 16; ++q){ DOT8(whh, hh4, q); }

    gl[0][tid] = a0;
    gl[1][tid] = a1;
    __syncthreads();   // gates ready -> elementwise; in4 free -> prefetch next

    if (t + 1 < SEQ) load_in(t + 1);

    if (tid < 128){
      const int r = tid >> 6, jp = tid & 63, j0 = jp*2;
      const float gi0 = gl[r][j0],         gi1 = gl[r][j0+1];
      const float gf0 = gl[r][HID+j0],     gf1 = gl[r][HID+j0+1];
      const float gg0 = gl[r][2*HID+j0],   gg1 = gl[r][2*HID+j0+1];
      const float go0 = gl[r][3*HID+j0],   go1 = gl[r][3*HID+j0+1];

      cA = sigm(gf0)*cA + sigm(gi0)*tanh_(gg0);
      cB = sigm(gf1)*cB + sigm(gi1)*tanh_(gg1);
      const float h0v = sigm(go0)*tanh_(cA);
      const float h1v = sigm(go1)*tanh_(cB);

      const uint32_t hp = pack2(h0v, h1v);
      hhu[r*64 + jp] = hp;

      const int b = b0 + r;
      if (h_out) h_out[(((size_t)t)*BATCH + b)*64 + jp] = hp;
      if (y_out){
        float* yp = y_out + ((size_t)t)*HID*BATCH + (size_t)j0*BATCH + b;
        yp[0]     = h0v;
        yp[BATCH] = h1v;
      }
    }
  }
#undef DOT8
}

extern "C" void kernel_launch(void* const* d_in, const int* in_sizes, int n_in,
                              void* d_out, int out_size, void* d_ws, size_t ws_size,
                              hipStream_t stream) {
  const float* x    = (const float*)d_in[0];
  const float* Wih0 = (const float*)d_in[1];
  const float* Whh0 = (const float*)d_in[2];
  const float* bih0 = (const float*)d_in[3];
  const float* bhh0 = (const float*)d_in[4];
  const float* Wih1 = (const float*)d_in[5];
  const float* Whh1 = (const float*)d_in[6];
  const float* bih1 = (const float*)d_in[7];
  const float* bhh1 = (const float*)d_in[8];
  const float* Wih2 = (const float*)d_in[9];
  const float* Whh2 = (const float*)d_in[10];
  const float* bih2 = (const float*)d_in[11];
  const float* bhh2 = (const float*)d_in[12];

  float* out = (float*)d_out;
  uint32_t* buf = (uint32_t*)d_ws;  // packed f16x2 [S][B][64] = 64 MiB

  dim3 grid(BATCH/2), block(512);

  // layer 0: x -> buf
  lstm_layer_kernel<<<grid, block, 0, stream>>>(
      Wih0, Whh0, bih0, bhh0, x, nullptr, buf, nullptr);
  // layer 1: buf -> buf (in-place safe: each block reads its (t,b) before writing it)
  lstm_layer_kernel<<<grid, block, 0, stream>>>(
      Wih1, Whh1, bih1, bhh1, nullptr, buf, buf, nullptr);
  // layer 2: buf -> out (S,H,B)
  lstm_layer_kernel<<<grid, block, 0, stream>>>(
      Wih2, Whh2, bih2, bhh2, nullptr, buf, nullptr, out);
}

// Round 2
// 1692.900 us; speedup vs baseline: 1.6600x; 1.6600x over previous
//
#include <hip/hip_runtime.h>
#include <stdint.h>

#define BATCH 512
#define SEQ   512
#define HID   128
#define BT    16       // batch tile per block
#define ROWB  528      // LDS act row stride in bytes (264 ushorts, 16B-aligned, bank-rotating)

typedef _Float16 half8 __attribute__((ext_vector_type(8)));
typedef float f32x4 __attribute__((ext_vector_type(4)));

union UHP { uint32_t u; _Float16 h[2]; };
__device__ __forceinline__ uint32_t pack2f(float a, float b){
  UHP r; r.h[0] = (_Float16)a; r.h[1] = (_Float16)b; return r.u;
}

__device__ __forceinline__ float rcp_(float x){
#if __has_builtin(__builtin_amdgcn_rcpf)
  return __builtin_amdgcn_rcpf(x);
#else
  return 1.f / x;
#endif
}
__device__ __forceinline__ float exp2_(float x){
#if __has_builtin(__builtin_amdgcn_exp2f)
  return __builtin_amdgcn_exp2f(x);
#else
  return exp2f(x);
#endif
}
// graceful at +-inf: sigm->{0,1}, tanh->{-1,1}; no clamps needed
__device__ __forceinline__ float sigm(float x){ return rcp_(1.f + exp2_(x * -1.44269504f)); }
__device__ __forceinline__ float tanh_(float x){ return 1.f - 2.f * rcp_(exp2_(x * 2.88539008f) + 1.f); }

// One LSTM layer. Grid: 32 blocks x 512 threads (8 waves). Block owns 16 batch rows.
// Wave w owns hidden units [16w,16w+16): acc tiles i,f,g,o for those units.
// act LDS layout per batch row b: ushort[264]: k<128 input x_t, 128<=k<256 h(t-1).
template<int MODE>   // 0: x fp32 in -> hbuf out; 1: hbuf in -> hbuf out (in place); 2: hbuf in -> y fp32 out
__global__ __launch_bounds__(512, 2) void lstm_mfma(
    const float* __restrict__ Wih, const float* __restrict__ Whh,
    const float* __restrict__ bih, const float* __restrict__ bhh,
    const float* __restrict__ x,
    uint32_t* __restrict__ hbuf,   // packed f16x2 [S][B][64]
    float* __restrict__ y)         // (S,H,B) fp32
{
  const int tid  = threadIdx.x;
  const int lane = tid & 63;
  const int w    = tid >> 6;       // wave 0..7
  const int u0   = w * 16;         // unit base of this wave
  const int rm   = lane & 15;      // A-row / D-col (batch) index
  const int kq   = lane >> 4;      // 0..3 k-quarter
  const int b0   = blockIdx.x * BT;

  __shared__ char act[BT * ROWB];

  // ---- one-time: weights -> f16 register fragments
  half8 wf[4][8];
  #pragma unroll
  for (int g = 0; g < 4; ++g){
    const int grow = g * HID + u0 + rm;
    #pragma unroll
    for (int s = 0; s < 8; ++s){
      const int k = s * 32 + kq * 8;
      const float* src = (s < 4) ? (Wih + (size_t)grow * HID + k)
                                 : (Whh + (size_t)grow * HID + (k - HID));
      const float4 aa = *(const float4*)src;
      const float4 bb = *(const float4*)(src + 4);
      half8 hh;
      hh[0]=(_Float16)aa.x; hh[1]=(_Float16)aa.y; hh[2]=(_Float16)aa.z; hh[3]=(_Float16)aa.w;
      hh[4]=(_Float16)bb.x; hh[5]=(_Float16)bb.y; hh[6]=(_Float16)bb.z; hh[7]=(_Float16)bb.w;
      wf[g][s] = hh;
    }
  }
  f32x4 bias4[4];
  #pragma unroll
  for (int g = 0; g < 4; ++g)
    #pragma unroll
    for (int r = 0; r < 4; ++r){
      const int row = g * HID + u0 + kq * 4 + r;
      bias4[g][r] = bih[row] + bhh[row];
    }

  // ---- input staging (all 512 threads): 16 rows x 128 f16 per step
  const int sb = tid >> 5;   // 0..15 batch row
  const int sk = tid & 31;   // 0..31 col group (4 elems)
  float4 pf0; uint2 pf1;
  auto issue_load = [&](int t){
    if constexpr (MODE == 0){
      pf0 = *(const float4*)(x + ((size_t)(b0 + sb) * SEQ + t) * HID + sk * 4);
    } else {
      pf1 = *(const uint2*)(hbuf + ((size_t)t * BATCH + b0 + sb) * 64 + sk * 2);
    }
  };
  auto write_in = [&](){
    uint2 v;
    if constexpr (MODE == 0){ v.x = pack2f(pf0.x, pf0.y); v.y = pack2f(pf0.z, pf0.w); }
    else v = pf1;
    *(uint2*)(act + sb * ROWB + sk * 8) = v;
  };

  // ---- prologue: stage input(0), zero h region
  issue_load(0); write_in();
  if (tid < 256)
    *(uint4*)(act + (tid >> 4) * ROWB + 256 + (tid & 15) * 16) = make_uint4(0u,0u,0u,0u);
  __syncthreads();

  f32x4 c4 = {0.f, 0.f, 0.f, 0.f};
  const int boff = rm * ROWB + kq * 16;   // B-frag base for this lane

  for (int t = 0; t < SEQ; ++t){
    if (t + 1 < SEQ) issue_load(t + 1);   // global prefetch overlaps compute

    f32x4 a0 = bias4[0], a1 = bias4[1], a2 = bias4[2], a3 = bias4[3];
    #pragma unroll
    for (int s = 0; s < 8; ++s){
      const half8 bf = *(const half8*)(act + boff + s * 64);
      a0 = __builtin_amdgcn_mfma_f32_16x16x32_f16(wf[0][s], bf, a0, 0, 0, 0);
      a1 = __builtin_amdgcn_mfma_f32_16x16x32_f16(wf[1][s], bf, a1, 0, 0, 0);
      a2 = __builtin_amdgcn_mfma_f32_16x16x32_f16(wf[2][s], bf, a2, 0, 0, 0);
      a3 = __builtin_amdgcn_mfma_f32_16x16x32_f16(wf[3][s], bf, a3, 0, 0, 0);
    }

    // elementwise fully in-register: lane holds i,f,g,o for 4 units, 1 batch col
    float hv[4];
    #pragma unroll
    for (int r = 0; r < 4; ++r){
      const float ii = sigm(a0[r]), ff = sigm(a1[r]);
      const float gg = tanh_(a2[r]), oo = sigm(a3[r]);
      c4[r] = ff * c4[r] + ii * gg;
      hv[r] = oo * tanh_(c4[r]);
    }
    const uint2 hp = { pack2f(hv[0], hv[1]), pack2f(hv[2], hv[3]) };

    if constexpr (MODE != 2){
      *(uint2*)(hbuf + ((size_t)t * BATCH + b0 + rm) * 64 + (u0 >> 1) + kq * 2) = hp;
    } else {
      const size_t ybase = ((size_t)t * HID + u0 + kq * 4) * BATCH + b0 + rm;
      y[ybase]             = hv[0];
      y[ybase + BATCH]     = hv[1];
      y[ybase + 2 * BATCH] = hv[2];
      y[ybase + 3 * BATCH] = hv[3];
    }

    __syncthreads();   // all B-frag reads of step t complete
    *(uint2*)(act + rm * ROWB + 256 + u0 * 2 + kq * 8) = hp;   // h(t) -> LDS
    if (t + 1 < SEQ) write_in();                               // x/h_in(t+1) -> LDS
    __syncthreads();   // writes visible for step t+1
  }
}

extern "C" void kernel_launch(void* const* d_in, const int* in_sizes, int n_in,
                              void* d_out, int out_size, void* d_ws, size_t ws_size,
                              hipStream_t stream) {
  const float* x    = (const float*)d_in[0];
  const float* Wih0 = (const float*)d_in[1];
  const float* Whh0 = (const float*)d_in[2];
  const float* bih0 = (const float*)d_in[3];
  const float* bhh0 = (const float*)d_in[4];
  const float* Wih1 = (const float*)d_in[5];
  const float* Whh1 = (const float*)d_in[6];
  const float* bih1 = (const float*)d_in[7];
  const float* bhh1 = (const float*)d_in[8];
  const float* Wih2 = (const float*)d_in[9];
  const float* Whh2 = (const float*)d_in[10];
  const float* bih2 = (const float*)d_in[11];
  const float* bhh2 = (const float*)d_in[12];

  float* out = (float*)d_out;
  uint32_t* buf = (uint32_t*)d_ws;   // packed f16x2 [S][B][64] = 64 MiB

  dim3 grid(BATCH / BT), block(512);

  lstm_mfma<0><<<grid, block, 0, stream>>>(Wih0, Whh0, bih0, bhh0, x, buf, nullptr);
  lstm_mfma<1><<<grid, block, 0, stream>>>(Wih1, Whh1, bih1, bhh1, nullptr, buf, nullptr);
  lstm_mfma<2><<<grid, block, 0, stream>>>(Wih2, Whh2, bih2, bhh2, nullptr, buf, out);
}

// Round 3
// 968.187 us; speedup vs baseline: 2.9026x; 1.7485x over previous
//
#include <hip/hip_runtime.h>
#include <stdint.h>

#define BATCH 512
#define SEQ   512
#define HID   128
#define BT    16        // batch tile per block
#define ROWB  528       // LDS act row stride in bytes
#define NTILE 32        // BATCH/BT
#define CH    8         // steps per sync chunk
#define RING  64        // ring slots (steps) per layer boundary

typedef _Float16 half8 __attribute__((ext_vector_type(8)));
typedef float f32x4 __attribute__((ext_vector_type(4)));
typedef unsigned long long u64;

union UHP { uint32_t u; _Float16 h[2]; };
__device__ __forceinline__ uint32_t pack2f(float a, float b){
  UHP r; r.h[0] = (_Float16)a; r.h[1] = (_Float16)b; return r.u;
}

__device__ __forceinline__ float rcp_(float x){
#if __has_builtin(__builtin_amdgcn_rcpf)
  return __builtin_amdgcn_rcpf(x);
#else
  return 1.f / x;
#endif
}
__device__ __forceinline__ float exp2_(float x){
#if __has_builtin(__builtin_amdgcn_exp2f)
  return __builtin_amdgcn_exp2f(x);
#else
  return exp2f(x);
#endif
}
__device__ __forceinline__ float sigm(float x){ return rcp_(1.f + exp2_(x * -1.44269504f)); }
__device__ __forceinline__ float tanh_(float x){ return 1.f - 2.f * rcp_(exp2_(x * 2.88539008f) + 1.f); }

// MODE 0: x fp32 -> ring0 ; MODE 1: ring0 -> ring1 ; MODE 2: ring1 -> y fp32
template<int MODE>
__device__ __forceinline__ void run_layer(
    const float* __restrict__ Wih, const float* __restrict__ Whh,
    const float* __restrict__ bih, const float* __restrict__ bhh,
    const float* __restrict__ x, uint32_t* __restrict__ rin,
    uint32_t* __restrict__ rout, float* __restrict__ y,
    int* src_ready, int* src_done, int* dst_ready, int* dst_done,
    int b0, char* act0, char* act1)
{
  const int tid  = threadIdx.x;
  const int lane = tid & 63;
  const int w    = tid >> 6;
  const int u0   = w * 16;
  const int rm   = lane & 15;   // batch col within tile
  const int kq   = lane >> 4;   // k-quarter / acc row group

  // ---- weights -> f16 register fragments (A: 16 units x 32 k per frag)
  half8 wf[4][8];
  #pragma unroll
  for (int g = 0; g < 4; ++g){
    const int grow = g * HID + u0 + rm;
    #pragma unroll
    for (int s = 0; s < 8; ++s){
      const int k = s * 32 + kq * 8;
      const float* src = (s < 4) ? (Wih + (size_t)grow * HID + k)
                                 : (Whh + (size_t)grow * HID + (k - HID));
      const float4 aa = *(const float4*)src;
      const float4 bb = *(const float4*)(src + 4);
      half8 hh;
      hh[0]=(_Float16)aa.x; hh[1]=(_Float16)aa.y; hh[2]=(_Float16)aa.z; hh[3]=(_Float16)aa.w;
      hh[4]=(_Float16)bb.x; hh[5]=(_Float16)bb.y; hh[6]=(_Float16)bb.z; hh[7]=(_Float16)bb.w;
      wf[g][s] = hh;
    }
  }
  f32x4 bias4[4];
  #pragma unroll
  for (int g = 0; g < 4; ++g)
    #pragma unroll
    for (int r = 0; r < 4; ++r){
      const int row = g * HID + u0 + kq * 4 + r;
      bias4[g][r] = bih[row] + bhh[row];
    }

  // ---- staging thread mapping: 16 rows x 128 f16
  const int sb = tid >> 5;   // 0..15 batch row
  const int sk = tid & 31;   // col group
  float4 pf0; u64 pf1;

  auto issue_load = [&](int t){
    if constexpr (MODE == 0){
      pf0 = *(const float4*)(x + ((size_t)(b0 + sb) * SEQ + t) * HID + sk * 4);
    } else {
      u64* p = (u64*)(rin + ((size_t)(t & (RING-1)) * BATCH + b0 + sb) * 64 + sk * 2);
      pf1 = __hip_atomic_load(p, __ATOMIC_RELAXED, __HIP_MEMORY_SCOPE_AGENT);
    }
  };
  auto write_in = [&](char* buf){
    if constexpr (MODE == 0){
      uint2 v; v.x = pack2f(pf0.x, pf0.y); v.y = pack2f(pf0.z, pf0.w);
      *(uint2*)(buf + sb * ROWB + sk * 8) = v;
    } else {
      *(u64*)(buf + sb * ROWB + sk * 8) = pf1;
    }
  };
  auto wait_src = [&](int chunks){       // consumer: wait for producer progress
    if constexpr (MODE != 0){
      while (__hip_atomic_load(src_ready, __ATOMIC_RELAXED, __HIP_MEMORY_SCOPE_AGENT) < chunks)
        __builtin_amdgcn_s_sleep(2);
    }
  };
  auto wait_dst = [&](int chunks){       // producer: ring back-pressure
    if constexpr (MODE != 2){
      while (__hip_atomic_load(dst_done, __ATOMIC_RELAXED, __HIP_MEMORY_SCOPE_AGENT) < chunks)
        __builtin_amdgcn_s_sleep(2);
    }
  };

  // ---- prologue: stage input(0) into buf0, zero h region of buf0
  wait_src(1);
  issue_load(0);
  write_in(act0);
  if (tid < 256)
    *(uint4*)(act0 + (tid >> 4) * ROWB + 256 + (tid & 15) * 16) = make_uint4(0u,0u,0u,0u);
  __syncthreads();

  f32x4 c4 = {0.f, 0.f, 0.f, 0.f};
  const int boff = rm * ROWB + kq * 16;
  int cur = 0;

  for (int t = 0; t < SEQ; ++t){
    char* bc = cur ? act1 : act0;
    char* bn = cur ? act0 : act1;
    const int tn = t + 1;

    if (tn < SEQ && (tn & (CH-1)) == 0) wait_src((tn >> 3) + 1);
    if ((t & (CH-1)) == 0 && t >= RING) wait_dst((t >> 3) - RING/CH + 1);
    if (tn < SEQ) issue_load(tn);       // global prefetch overlaps compute

    f32x4 a0 = bias4[0], a1 = bias4[1], a2 = bias4[2], a3 = bias4[3];
    #pragma unroll
    for (int s = 0; s < 8; ++s){
      const half8 bf = *(const half8*)(bc + boff + s * 64);
      a0 = __builtin_amdgcn_mfma_f32_16x16x32_f16(wf[0][s], bf, a0, 0, 0, 0);
      a1 = __builtin_amdgcn_mfma_f32_16x16x32_f16(wf[1][s], bf, a1, 0, 0, 0);
      a2 = __builtin_amdgcn_mfma_f32_16x16x32_f16(wf[2][s], bf, a2, 0, 0, 0);
      a3 = __builtin_amdgcn_mfma_f32_16x16x32_f16(wf[3][s], bf, a3, 0, 0, 0);
    }

    float hv[4];
    #pragma unroll
    for (int r = 0; r < 4; ++r){
      const float ii = sigm(a0[r]), ff = sigm(a1[r]);
      const float gg = tanh_(a2[r]), oo = sigm(a3[r]);
      c4[r] = ff * c4[r] + ii * gg;
      hv[r] = oo * tanh_(c4[r]);
    }
    const uint2 hp = { pack2f(hv[0], hv[1]), pack2f(hv[2], hv[3]) };

    if constexpr (MODE != 2){
      const u64 hp64 = ((u64)hp.y << 32) | (u64)hp.x;
      u64* p = (u64*)(rout + ((size_t)(t & (RING-1)) * BATCH + b0 + rm) * 64 + (u0 >> 1) + kq * 2);
      __hip_atomic_store(p, hp64, __ATOMIC_RELAXED, __HIP_MEMORY_SCOPE_AGENT);
    } else {
      const size_t yb = ((size_t)t * HID + u0 + kq * 4) * BATCH + b0 + rm;
      y[yb]             = hv[0];
      y[yb + BATCH]     = hv[1];
      y[yb + 2 * BATCH] = hv[2];
      y[yb + 3 * BATCH] = hv[3];
    }

    // next-step operands -> other buffer; single barrier per step
    *(uint2*)(bn + rm * ROWB + 256 + u0 * 2 + kq * 8) = hp;
    if (tn < SEQ) write_in(bn);
    __syncthreads();

    if ((t & (CH-1)) == (CH-1) && tid == 0){
      const int cdone = (t >> 3) + 1;
      if constexpr (MODE != 2){
        __threadfence();
        __hip_atomic_store(dst_ready, cdone, __ATOMIC_RELAXED, __HIP_MEMORY_SCOPE_AGENT);
      }
      if constexpr (MODE != 0){
        __hip_atomic_store(src_done, cdone, __ATOMIC_RELAXED, __HIP_MEMORY_SCOPE_AGENT);
      }
    }
    cur ^= 1;
  }
}

__global__ __launch_bounds__(512, 2) void lstm_pipe(
    const float* W0i, const float* W0h, const float* b0i, const float* b0h,
    const float* W1i, const float* W1h, const float* b1i, const float* b1h,
    const float* W2i, const float* W2h, const float* b2i, const float* b2h,
    const float* x, float* y, uint32_t* ring, int* flags)
{
  const int layer = blockIdx.x >> 5;   // 0,1,2  (layer0 blocks dispatch first)
  const int tile  = blockIdx.x & 31;
  const int b0    = tile * BT;

  __shared__ char act[2][BT * ROWB];

  uint32_t* r0 = ring;                                  // boundary 0: layer0 -> layer1
  uint32_t* r1 = ring + (size_t)RING * BATCH * 64;      // boundary 1: layer1 -> layer2

  // flags: prod[2][32] at [0..63], cons[2][32] at [64..127]
  int* p0 = flags + 0*NTILE + tile;
  int* p1 = flags + 1*NTILE + tile;
  int* c0 = flags + 2*NTILE + 0*NTILE + tile;
  int* c1 = flags + 2*NTILE + 1*NTILE + tile;

  if (layer == 0){
    run_layer<0>(W0i, W0h, b0i, b0h, x, nullptr, r0, nullptr,
                 nullptr, nullptr, p0, c0, b0, act[0], act[1]);
  } else if (layer == 1){
    run_layer<1>(W1i, W1h, b1i, b1h, nullptr, r0, r1, nullptr,
                 p0, c0, p1, c1, b0, act[0], act[1]);
  } else {
    run_layer<2>(W2i, W2h, b2i, b2h, nullptr, r1, nullptr, y,
                 p1, c1, nullptr, nullptr, b0, act[0], act[1]);
  }
}

extern "C" void kernel_launch(void* const* d_in, const int* in_sizes, int n_in,
                              void* d_out, int out_size, void* d_ws, size_t ws_size,
                              hipStream_t stream) {
  const float* x    = (const float*)d_in[0];
  const float* Wih0 = (const float*)d_in[1];
  const float* Whh0 = (const float*)d_in[2];
  const float* bih0 = (const float*)d_in[3];
  const float* bhh0 = (const float*)d_in[4];
  const float* Wih1 = (const float*)d_in[5];
  const float* Whh1 = (const float*)d_in[6];
  const float* bih1 = (const float*)d_in[7];
  const float* bhh1 = (const float*)d_in[8];
  const float* Wih2 = (const float*)d_in[9];
  const float* Whh2 = (const float*)d_in[10];
  const float* bih2 = (const float*)d_in[11];
  const float* bhh2 = (const float*)d_in[12];

  float* out = (float*)d_out;
  uint32_t* ring = (uint32_t*)d_ws;
  const size_t ring_bytes = (size_t)2 * RING * BATCH * 64 * 4;   // 16 MiB
  int* flags = (int*)((char*)d_ws + ring_bytes);

  hipMemsetAsync(flags, 0, 4 * NTILE * sizeof(int), stream);

  dim3 grid(3 * NTILE), block(512);
  lstm_pipe<<<grid, block, 0, stream>>>(
      Wih0, Whh0, bih0, bhh0, Wih1, Whh1, bih1, bhh1, Wih2, Whh2, bih2, bhh2,
      x, out, ring, flags);
}